// Round 3
// baseline (3655.532 us; speedup 1.0000x reference)
//
#include <hip/hip_runtime.h>
#include <hip/hip_bf16.h>
#include <math.h>

// ---------------------------------------------------------------------------
// DNC forward on MI355X.
//   k_detect  : device-side input-dtype detection (f32 vs bf16) + bar zero
//   k_convert : canonicalize all inputs -> internal bf16/f32 buffers
//   k_lstm    : persistent 64-block kernel; layer0(t) & layer1(t-1) pipelined,
//               weights-stationary bf16 MFMA (16x16x32), 33 grid barriers
//   k_xi      : interface GEMM (2048 x 480 x 512) MFMA
//   k_mem     : memory recurrence, 1 block / batch, 32 steps, no grid sync
//   k_tanhy   : tanh([out, rvec]) -> bf16
//   k_out     : output GEMM (2048 x 256 x 768) MFMA -> d_out (dtype per flag)
// ---------------------------------------------------------------------------

typedef __bf16 bf16_t;
typedef __attribute__((ext_vector_type(8))) __bf16 bf16x8;
typedef __attribute__((ext_vector_type(4))) float f32x4;

#define B_    64
#define T_    32
#define IN_   256
#define H_    512
#define M_    256
#define W_    64
#define R_    4
#define IFACE_ 471
#define DELTA_ 1e-6f

// ---------------- ws layout (bytes) ----------------
#define OFF_H0SEQ  (0L)
#define SZ_H0SEQ   (32L*64*512*2)
#define OFF_OUTSEQ (OFF_H0SEQ + SZ_H0SEQ)
#define SZ_OUTSEQ  (32L*64*512*2)
#define OFF_H0BUF  (OFF_OUTSEQ + SZ_OUTSEQ)
#define SZ_HBUF    (2L*64*512*2)
#define OFF_H1BUF  (OFF_H0BUF + SZ_HBUF)
#define OFF_XI     (OFF_H1BUF + SZ_HBUF)
#define SZ_XI      (32L*64*480*4)
#define OFF_RVEC   (OFF_XI + SZ_XI)
#define SZ_RVEC    (32L*64*256*4)
#define OFF_YBF    (OFF_RVEC + SZ_RVEC)
#define SZ_YBF     (32L*64*768*2)
#define OFF_MEM    (OFF_YBF + SZ_YBF)
#define SZ_MEM     (64L*256*64*4)
#define OFF_LINK   (OFF_MEM + SZ_MEM)
#define SZ_LINK    (64L*256*256*4)
#define OFF_BAR    (OFF_LINK + SZ_LINK)
#define SZ_BAR     (256L)                 // bar[2] + flag
#define OFF_XB     (OFF_BAR + SZ_BAR)
#define SZ_XB      (64L*32*256*2)
#define OFF_H0B    (OFF_XB + SZ_XB)
#define SZ_H0B     (2L*64*512*2)
#define OFF_W0     (OFF_H0B + SZ_H0B)
#define SZ_W       (2048L*512*2)
#define OFF_W1     (OFF_W0 + SZ_W)
#define OFF_W2     (OFF_W1 + SZ_W)
#define OFF_W3     (OFF_W2 + SZ_W)
#define OFF_WIF    (OFF_W3 + SZ_W)
#define SZ_WIF     (480L*512*2)
#define OFF_WOUTB  (OFF_WIF + SZ_WIF)
#define SZ_WOUTB   (256L*768*2)
#define OFF_BS0    (OFF_WOUTB + SZ_WOUTB)
#define SZ_BS      (2048L*4)
#define OFF_BS1    (OFF_BS0 + SZ_BS)
#define OFF_BIF    (OFF_BS1 + SZ_BS)
#define SZ_BIF     (2048L)
#define OFF_BOUTF  (OFF_BIF + SZ_BIF)
#define SZ_BOUTF   (1024L)                // total ~45.1 MB

__device__ __forceinline__ float sigf(float x){ return 1.0f/(1.0f + expf(-x)); }
__device__ __forceinline__ float softplusf(float x){
  return fmaxf(x, 0.0f) + log1pf(expf(-fabsf(x)));
}
__device__ __forceinline__ float wred(float v){
  #pragma unroll
  for (int off = 32; off; off >>= 1) v += __shfl_xor(v, off, 64);
  return v;
}
__device__ __forceinline__ float ldin(const void* p, long i, int mf){
  return mf ? ((const float*)p)[i] : (float)((const bf16_t*)p)[i];
}

// agent-scope generation barrier; all gridDim.x blocks must call
__device__ __forceinline__ void gridbar(unsigned* cnt, unsigned* gen, unsigned nb){
  __syncthreads();
  if (threadIdx.x == 0){
    unsigned g = __hip_atomic_load(gen, __ATOMIC_ACQUIRE, __HIP_MEMORY_SCOPE_AGENT);
    unsigned a = __hip_atomic_fetch_add(cnt, 1u, __ATOMIC_ACQ_REL, __HIP_MEMORY_SCOPE_AGENT);
    if (a == nb - 1u){
      __hip_atomic_store(cnt, 0u, __ATOMIC_RELAXED, __HIP_MEMORY_SCOPE_AGENT);
      __hip_atomic_fetch_add(gen, 1u, __ATOMIC_ACQ_REL, __HIP_MEMORY_SCOPE_AGENT);
    } else {
      while (__hip_atomic_load(gen, __ATOMIC_ACQUIRE, __HIP_MEMORY_SCOPE_AGENT) == g)
        __builtin_amdgcn_s_sleep(2);
    }
  }
  __syncthreads();
}

// ---------------------------------------------------------------------------
// Detect input dtype from x's raw halfwords. f32 N(0,1): even uint16s are
// mantissa-low (uniform) -> ~47% have bf16-exponent>=0x88 (|v|>=512).
// bf16 N(0,1): values bounded ~6 -> zero hits.
__global__ void k_detect(const unsigned short* __restrict__ x16,
                         int* __restrict__ flag, unsigned* __restrict__ bar){
  __shared__ int cnt;
  if (threadIdx.x == 0){ cnt = 0; bar[0] = 0u; bar[1] = 0u; }
  __syncthreads();
  unsigned short u = x16[threadIdx.x * 2];
  int e = (u >> 7) & 0xFF;
  if (e >= 0x88) atomicAdd(&cnt, 1);
  __syncthreads();
  if (threadIdx.x == 0) *flag = (cnt > 16) ? 1 : 0;
}

// ---------------------------------------------------------------------------
__global__ void k_convert(const void* x, const void* h0, const void* Wih0,
                          const void* Whh0, const void* bih0, const void* bhh0,
                          const void* Wih1, const void* Whh1, const void* bih1,
                          const void* bhh1, const void* Wif, const void* bif,
                          const void* Wout, const void* bout,
                          bf16_t* __restrict__ xb, bf16_t* __restrict__ h0b,
                          bf16_t* __restrict__ h0buf, bf16_t* __restrict__ h1buf,
                          bf16_t* __restrict__ W0, bf16_t* __restrict__ W1,
                          bf16_t* __restrict__ W2, bf16_t* __restrict__ W3,
                          bf16_t* __restrict__ Wifp, bf16_t* __restrict__ Woutb,
                          float* __restrict__ bs0, float* __restrict__ bs1,
                          float* __restrict__ bifp, float* __restrict__ boutf,
                          const int* __restrict__ flag)
{
  const int mf = *flag;
  const long stride = (long)gridDim.x * blockDim.x;
  long i0 = (long)blockIdx.x * blockDim.x + threadIdx.x;
  switch (blockIdx.y){
  case 0: for (long i = i0; i < 64L*32*256; i += stride) xb[i] = (bf16_t)ldin(x, i, mf); break;
  case 1: for (long i = i0; i < 2L*64*512; i += stride){
            float v = ldin(h0, i, mf); bf16_t bb = (bf16_t)v; h0b[i] = bb;
            if (i < 64*512) h0buf[i] = bb; else h1buf[i - 64*512] = bb;
          } break;
  case 2: for (long i = i0; i < 2048L*512; i += stride) W0[i] = (bf16_t)ldin(Wih0, i, mf); break;
  case 3: for (long i = i0; i < 2048L*512; i += stride) W1[i] = (bf16_t)ldin(Whh0, i, mf); break;
  case 4: for (long i = i0; i < 2048L*512; i += stride) W2[i] = (bf16_t)ldin(Wih1, i, mf); break;
  case 5: for (long i = i0; i < 2048L*512; i += stride) W3[i] = (bf16_t)ldin(Whh1, i, mf); break;
  case 6: for (long i = i0; i < 480L*512; i += stride){
            long r = i >> 9;
            Wifp[i] = (r < IFACE_) ? (bf16_t)ldin(Wif, i, mf) : (bf16_t)0.0f;
          } break;
  case 7: for (long i = i0; i < 256L*768; i += stride) Woutb[i] = (bf16_t)ldin(Wout, i, mf); break;
  case 8:
    for (long i = i0; i < 2048; i += stride){
      bs0[i] = ldin(bih0, i, mf) + ldin(bhh0, i, mf);
      bs1[i] = ldin(bih1, i, mf) + ldin(bhh1, i, mf);
    }
    for (long i = i0; i < 480; i += stride) bifp[i] = (i < IFACE_) ? ldin(bif, i, mf) : 0.0f;
    for (long i = i0; i < 256; i += stride) boutf[i] = ldin(bout, i, mf);
    break;
  }
}

// ---------------------------------------------------------------------------
// Persistent LSTM.  blocks 0..31: layer0 (units bid*16..+16); 32..63: layer1.
// MFMA 16x16x32 bf16: A[m=lane&15][k=(lane>>4)*8+j]; B[k][n=lane&15];
// D[m=(lane>>4)*4+v][n=lane&15].  M=batch tile, N=gate-row tile.
__global__ __launch_bounds__(256,1) void k_lstm(
    const bf16_t* __restrict__ xb, const bf16_t* __restrict__ h0b,
    const bf16_t* __restrict__ W0, const bf16_t* __restrict__ W1,
    const bf16_t* __restrict__ W2, const bf16_t* __restrict__ W3,
    const float* __restrict__ bs0, const float* __restrict__ bs1,
    bf16_t* __restrict__ h0buf, bf16_t* __restrict__ h1buf,
    bf16_t* __restrict__ h0seq, bf16_t* __restrict__ outseq,
    unsigned* __restrict__ bar)
{
  __shared__ float cst[64][16];   // c-state [batch][unit-local]
  __shared__ float bias[4][16];

  const int bid = blockIdx.x;
  const int layer = bid >> 5;
  const int u0 = (bid & 31) * 16;
  const int tid = threadIdx.x;
  const int lane = tid & 63;
  const int wv = tid >> 6;        // 4 waves
  const int m16 = lane & 15, q = lane >> 4;

  for (int i = tid; i < 64*16; i += 256){
    int b = i >> 4, n = i & 15;
    cst[b][n] = (float)h0b[layer*(64*512) + b*512 + u0 + n];  // c init = h init
  }
  if (tid < 64){
    int G = tid >> 4, n = tid & 15;
    const float* bs = layer ? bs1 : bs0;
    bias[G][n] = bs[G*512 + u0 + n];
  }
  __syncthreads();

  const bf16_t* Wi = layer ? W2 : W0;
  const bf16_t* Wh = layer ? W3 : W1;
  bf16_t* hbuf = layer ? h1buf : h0buf;

  for (int ps = 0; ps <= 32; ++ps){
    const int t = layer ? (ps - 1) : ps;
    const bool active = layer ? (ps >= 1) : (ps < 32);
    if (active){
      const int p = t & 1;
      const bf16_t* hin = hbuf + p*(64*512);
      bf16_t* hout = hbuf + (p^1)*(64*512);
      const int b0 = wv * 16;

      f32x4 acc[4];
      #pragma unroll
      for (int G = 0; G < 4; ++G){ float bv = bias[G][m16]; acc[G] = (f32x4){bv,bv,bv,bv}; }

      const int nkt = layer ? 32 : 24;
      for (int kt = 0; kt < nkt; ++kt){
        const bf16_t* asrc;
        const bf16_t* wbase; int kcol;
        if (!layer){
          if (kt < 8){ asrc = xb + ((size_t)(b0+m16)*T_ + t)*IN_ + kt*32 + q*8;
                       wbase = Wi; kcol = kt*32; }        // x part (cols 0..255 of Wih0)
          else       { asrc = hin + (b0+m16)*512 + (kt-8)*32 + q*8;
                       wbase = Wh; kcol = (kt-8)*32; }
        } else {
          if (kt < 16){ asrc = h0seq + ((size_t)t*64 + b0+m16)*512 + kt*32 + q*8;
                        wbase = Wi; kcol = kt*32; }
          else        { asrc = hin + (b0+m16)*512 + (kt-16)*32 + q*8;
                        wbase = Wh; kcol = (kt-16)*32; }
        }
        bf16x8 afrag = *(const bf16x8*)asrc;
        #pragma unroll
        for (int G = 0; G < 4; ++G){
          const bf16_t* bsrc = wbase + (size_t)(G*512 + u0 + m16)*512 + kcol + q*8;
          bf16x8 bfrag = *(const bf16x8*)bsrc;
          acc[G] = __builtin_amdgcn_mfma_f32_16x16x32_bf16(afrag, bfrag, acc[G], 0, 0, 0);
        }
      }
      // cell update: lane holds batches b0+q*4+v, unit u0+m16
      #pragma unroll
      for (int v = 0; v < 4; ++v){
        int b = b0 + q*4 + v;
        float gi = acc[0][v], gf = acc[1][v], gg = acc[2][v], go = acc[3][v];
        float c_ = sigf(gf)*cst[b][m16] + sigf(gi)*tanhf(gg);
        cst[b][m16] = c_;
        float h = sigf(go)*tanhf(c_);
        bf16_t hb = (bf16_t)h;
        hout[b*512 + u0 + m16] = hb;
        if (!layer) h0seq[((size_t)t*64 + b)*512 + u0 + m16] = hb;
        else        outseq[((size_t)t*64 + b)*512 + u0 + m16] = hb;   // clip(+-20) no-op, |h|<1
      }
    }
    gridbar(bar, bar + 1, gridDim.x);
  }
}

// ---------------------------------------------------------------------------
__global__ __launch_bounds__(256,1) void k_xi(
    const bf16_t* __restrict__ outseq, const bf16_t* __restrict__ Wifp,
    const float* __restrict__ bifp, float* __restrict__ XI)
{
  const int mt = blockIdx.x;            // 0..127
  const int tid = threadIdx.x, lane = tid & 63, wv = tid >> 6;
  const int nt = blockIdx.y*4 + wv;     // 0..31
  if (nt >= 30) return;                 // 30 tiles cover 480 cols
  const int m16 = lane & 15, q = lane >> 4;
  const int r = nt*16 + m16;            // < 480, rows 471..479 of Wifp are zero
  float bv = bifp[r];
  f32x4 acc = {bv,bv,bv,bv};
  const bf16_t* arow = outseq + (size_t)(mt*16 + m16)*512 + q*8;
  const bf16_t* brow = Wifp + (size_t)r*512 + q*8;
  for (int kt = 0; kt < 16; ++kt){
    bf16x8 a = *(const bf16x8*)(arow + kt*32);
    bf16x8 bb = *(const bf16x8*)(brow + kt*32);
    acc = __builtin_amdgcn_mfma_f32_16x16x32_bf16(a, bb, acc, 0, 0, 0);
  }
  #pragma unroll
  for (int v = 0; v < 4; ++v){
    int row = mt*16 + q*4 + v;
    XI[(size_t)row*480 + nt*16 + m16] = acc[v];
  }
}

// ---------------------------------------------------------------------------
__device__ __forceinline__ void softmax256_wave(float* a, int lane){
  float v0=a[lane], v1=a[64+lane], v2=a[128+lane], v3=a[192+lane];
  float mx = fmaxf(fmaxf(v0,v1), fmaxf(v2,v3));
  #pragma unroll
  for (int off=32; off; off>>=1) mx = fmaxf(mx, __shfl_xor(mx, off, 64));
  v0=expf(v0-mx); v1=expf(v1-mx); v2=expf(v2-mx); v3=expf(v3-mx);
  float s = v0+v1+v2+v3;
  #pragma unroll
  for (int off=32; off; off>>=1) s += __shfl_xor(s, off, 64);
  float inv = 1.0f/s;
  a[lane]=v0*inv; a[64+lane]=v1*inv; a[128+lane]=v2*inv; a[192+lane]=v3*inv;
}

// one block per batch; 1024 threads = 16 waves
__global__ __launch_bounds__(1024,1) void k_mem(
    const float* __restrict__ XI, float* __restrict__ MEM,
    float* __restrict__ LINK, float* __restrict__ RVEC)
{
  const int b = blockIdx.x;
  const int tid = threadIdx.x, lane = tid & 63, wv = tid >> 6;
  float* memb  = MEM  + (size_t)b*(256*64);
  float* linkb = LINK + (size_t)b*(256*256);

  __shared__ float xib[480];
  __shared__ float rkn[4][64], wkn[64], ev_[64], wvv[64];
  __shared__ float rs_[4], fg_[4], rm_[4][3];
  __shared__ float wsS, agS, wgS, wwsumS;
  __shared__ float invn[256], wcw[256];
  __shared__ float usage[256], uu[256], alloc_[256], su[256], scanA[256];
  __shared__ int   rank_[256], rnk4[256][4];
  __shared__ float ww_[256], prec_[256];
  __shared__ float rw_[4][256], fwd_[4][256], bwd_[4][256], rcw_[4][256];
  __shared__ float rvl[4][64];

  // ---- init state ----
  { int r = tid >> 8, m = tid & 255; rw_[r][m] = DELTA_; }
  if (tid < 256){
    ww_[tid] = DELTA_; usage[tid] = 0.0f; prec_[tid] = 0.0f;
    invn[tid] = 1.0f/(sqrtf(64.0f*DELTA_*DELTA_) + DELTA_);
  }
  { f32x4 dv = {DELTA_,DELTA_,DELTA_,DELTA_}, zv = {0,0,0,0};
    f32x4* m4 = (f32x4*)memb;  for (int i = tid; i < 4096;  i += 1024) m4[i] = dv;
    f32x4* l4 = (f32x4*)linkb; for (int i = tid; i < 16384; i += 1024) l4[i] = zv; }
  __syncthreads();

  for (int t = 0; t < 32; ++t){
    const float* xi = XI + ((size_t)t*64 + b)*480;
    // ---- phase 0: parse interface vector ----
    if (tid < IFACE_) xib[tid] = xi[tid];
    __syncthreads();
    if (wv < 4){                                  // read keys: tanh + normalize
      float v = tanhf(xib[wv*64 + lane]);
      float s = wred(v*v);
      rkn[wv][lane] = v/(sqrtf(s) + DELTA_);
    } else if (wv == 4){                          // write key
      float v = tanhf(xib[260 + lane]);
      float s = wred(v*v);
      wkn[lane] = v/(sqrtf(s) + DELTA_);
    } else if (wv == 5){ ev_[lane] = sigf(xib[325 + lane]);
    } else if (wv == 6){ wvv[lane] = tanhf(xib[389 + lane]);
    } else if (wv == 7){
      if (lane < 4)        rs_[lane] = softplusf(xib[256 + lane]);
      else if (lane == 4)  wsS = softplusf(xib[324]);
      else if (lane < 9)   fg_[lane-5] = sigf(xib[453 + (lane-5)]);
      else if (lane == 9)  agS = sigf(xib[457]);
      else if (lane == 10) wgS = sigf(xib[458]);
      else if (lane >= 16 && lane < 20){
        int r = lane - 16;
        float a0 = xib[459+r*3], a1 = xib[459+r*3+1], a2 = xib[459+r*3+2];
        float mx = fmaxf(a0, fmaxf(a1, a2));
        float e0 = expf(a0-mx), e1 = expf(a1-mx), e2 = expf(a2-mx);
        float s = e0+e1+e2;
        rm_[r][0]=e0/s; rm_[r][1]=e1/s; rm_[r][2]=e2/s;
      }
    }
    __syncthreads();

    // ---- phase 1: usage update (OLD ww, OLD rw) ----
    if (tid < 256){
      int m = tid;
      float us = usage[m] + (1.0f - usage[m])*ww_[m];
      float psi = (1.0f - fg_[0]*rw_[0][m]) * (1.0f - fg_[1]*rw_[1][m])
                * (1.0f - fg_[2]*rw_[2][m]) * (1.0f - fg_[3]*rw_[3][m]);
      us *= psi;
      usage[m] = us;
      uu[m] = DELTA_ + (1.0f - DELTA_)*us;
    }
    __syncthreads();

    // ---- phase 2: write content weights on OLD mem ----
    #pragma unroll 1
    for (int i = 0; i < 16; ++i){
      int m = wv*16 + i;
      float mv = memb[m*64 + lane];
      float s = wred(mv * wkn[lane]);
      if (lane == 0) wcw[m] = wsS * s * invn[m];
    }
    __syncthreads();
    if (wv == 0) softmax256_wave(wcw, lane);
    __syncthreads();

    // ---- phase 3: allocation via stable rank-sort + exclusive cumprod ----
    { int i = tid >> 2, jc = tid & 3;
      float ui = uu[i]; int cnt = 0;
      for (int s = 0; s < 64; ++s){
        int j = jc*64 + s; float uj = uu[j];
        cnt += (uj < ui || (uj == ui && j < i)) ? 1 : 0;
      }
      rnk4[i][jc] = cnt; }
    __syncthreads();
    if (tid < 256){
      int r = rnk4[tid][0] + rnk4[tid][1] + rnk4[tid][2] + rnk4[tid][3];
      rank_[tid] = r;
      su[r] = uu[tid];
    }
    __syncthreads();
    if (wv == 0){   // exclusive product scan of su -> scanA (single wave)
      int base = lane*4;
      float v0 = su[base], v1 = su[base+1], v2 = su[base+2];
      float p1 = v0*v1, p2 = p1*v2, p3 = p2*su[base+3];
      float sc = p3;
      #pragma unroll
      for (int off = 1; off < 64; off <<= 1){
        float n = __shfl_up(sc, off, 64);
        if (lane >= off) sc *= n;
      }
      float exch = __shfl_up(sc, 1, 64);
      if (lane == 0) exch = 1.0f;
      scanA[base] = exch; scanA[base+1] = exch*v0;
      scanA[base+2] = exch*p1; scanA[base+3] = exch*p2;
    }
    __syncthreads();
    if (tid < 256) alloc_[tid] = (1.0f - uu[tid]) * scanA[rank_[tid]];
    __syncthreads();

    // ---- phase 4: write weights + zero bwd ----
    if (tid < 256) ww_[tid] = wgS*(agS*alloc_[tid] + (1.0f - agS)*wcw[tid]);
    { int r = tid >> 8, m = tid & 255; bwd_[r][m] = 0.0f; }
    __syncthreads();
    if (wv == 0){
      float s = wred(ww_[lane] + ww_[64+lane] + ww_[128+lane] + ww_[192+lane]);
      if (lane == 0) wwsumS = s;
    }
    __syncthreads();

    // ---- phase 5: mem erase/write + new norms + read-content pre-softmax ----
    float mrow[16];
    #pragma unroll 1
    for (int i = 0; i < 16; ++i){
      int m = wv*16 + i;
      float wm = ww_[m];
      float old = memb[m*64 + lane];
      float mn = old*(1.0f - wm*ev_[lane]) + wm*wvv[lane];
      memb[m*64 + lane] = mn;
      mrow[i] = mn;
      float s = wred(mn*mn);
      float inv = 1.0f/(sqrtf(s) + DELTA_);
      if (lane == 0) invn[m] = inv;
      #pragma unroll
      for (int r = 0; r < 4; ++r){
        float sr = wred(mn * rkn[r][lane]);
        if (lane == 0) rcw_[r][m] = rs_[r]*sr*inv;
      }
    }
    __syncthreads();
    if (wv < 4) softmax256_wave(rcw_[wv], lane);
    __syncthreads();

    // ---- phase 6: link update + fwd + bwd, single fused sweep ----
    { const int c0 = lane*4;
      float wwv4[4], pv[4], rwc[4][4], bacc[4][4];
      #pragma unroll
      for (int ci = 0; ci < 4; ++ci){ wwv4[ci] = ww_[c0+ci]; pv[ci] = prec_[c0+ci]; }
      #pragma unroll
      for (int r = 0; r < 4; ++r)
        #pragma unroll
        for (int ci = 0; ci < 4; ++ci){ rwc[r][ci] = rw_[r][c0+ci]; bacc[r][ci] = 0.0f; }
      #pragma unroll 1
      for (int i = 0; i < 16; ++i){
        int j = wv*16 + i;
        float wj = ww_[j];
        float rwj[4];
        #pragma unroll
        for (int r = 0; r < 4; ++r) rwj[r] = rw_[r][j];
        f32x4 L = ((const f32x4*)(linkb + (size_t)j*256))[lane];
        float ln[4], fpart[4] = {0,0,0,0};
        #pragma unroll
        for (int ci = 0; ci < 4; ++ci){
          float v = (1.0f - wj - wwv4[ci])*L[ci] + wj*pv[ci];
          if (c0 + ci == j) v = 0.0f;
          ln[ci] = v;
          #pragma unroll
          for (int r = 0; r < 4; ++r){
            fpart[r] += v*rwc[r][ci];
            bacc[r][ci] += rwj[r]*v;
          }
        }
        f32x4 Lo = {ln[0], ln[1], ln[2], ln[3]};
        ((f32x4*)(linkb + (size_t)j*256))[lane] = Lo;
        #pragma unroll
        for (int r = 0; r < 4; ++r){
          float s = wred(fpart[r]);
          if (lane == 0) fwd_[r][j] = s;
        }
      }
      #pragma unroll
      for (int r = 0; r < 4; ++r)
        #pragma unroll
        for (int ci = 0; ci < 4; ++ci)
          atomicAdd(&bwd_[r][c0+ci], bacc[r][ci]);
    }
    __syncthreads();

    // ---- phase 7/9: precedence + new read weights ----
    if (tid < 256) prec_[tid] = (1.0f - wwsumS)*prec_[tid] + ww_[tid];
    { int r = tid >> 8, m = tid & 255;
      rw_[r][m] = rm_[r][0]*bwd_[r][m] + rm_[r][1]*fwd_[r][m] + rm_[r][2]*rcw_[r][m]; }
    __syncthreads();

    // ---- phase 10: read vectors ----
    if (tid < 256) rvl[tid>>6][tid&63] = 0.0f;
    __syncthreads();
    { float racc[4] = {0,0,0,0};
      #pragma unroll 1
      for (int i = 0; i < 16; ++i){
        int m = wv*16 + i;
        #pragma unroll
        for (int r = 0; r < 4; ++r) racc[r] += rw_[r][m]*mrow[i];
      }
      #pragma unroll
      for (int r = 0; r < 4; ++r) atomicAdd(&rvl[r][lane], racc[r]); }
    __syncthreads();
    if (tid < 256) RVEC[((size_t)t*64 + b)*256 + tid] = rvl[tid>>6][tid&63];
    __syncthreads();
  }
}

// ---------------------------------------------------------------------------
__global__ void k_tanhy(const bf16_t* __restrict__ outseq, const float* __restrict__ RVEC,
                        bf16_t* __restrict__ Y){
  const int n = 2048*768;
  for (int i = blockIdx.x*blockDim.x + threadIdx.x; i < n; i += gridDim.x*blockDim.x){
    int row = i / 768, j = i - row*768;
    float v = (j < 512) ? (float)outseq[(size_t)row*512 + j] : RVEC[(size_t)row*256 + (j - 512)];
    Y[i] = (bf16_t)tanhf(v);
  }
}

__global__ __launch_bounds__(256,1) void k_out(
    const bf16_t* __restrict__ Y, const bf16_t* __restrict__ Woutb,
    const float* __restrict__ boutf, void* __restrict__ dout,
    const int* __restrict__ flag)
{
  const int mf = *flag;
  const int mt = blockIdx.x;          // 0..127
  const int tid = threadIdx.x, lane = tid & 63, wv = tid >> 6;
  const int nt = blockIdx.y*4 + wv;   // 0..15
  const int m16 = lane & 15, q = lane >> 4;
  const int o = nt*16 + m16;
  float bv = boutf[o];
  f32x4 acc = {bv,bv,bv,bv};
  const bf16_t* arow = Y + (size_t)(mt*16 + m16)*768 + q*8;
  const bf16_t* brow = Woutb + (size_t)o*768 + q*8;
  for (int kt = 0; kt < 24; ++kt){
    acc = __builtin_amdgcn_mfma_f32_16x16x32_bf16(
        *(const bf16x8*)(arow + kt*32), *(const bf16x8*)(brow + kt*32), acc, 0, 0, 0);
  }
  #pragma unroll
  for (int v = 0; v < 4; ++v){
    int row = mt*16 + q*4 + v;        // = t*64 + b
    int b = row & 63, t = row >> 6;
    size_t idx = ((size_t)b*T_ + t)*256 + o;
    if (mf) ((float*)dout)[idx] = acc[v];
    else    ((bf16_t*)dout)[idx] = (bf16_t)acc[v];
  }
}

// ---------------------------------------------------------------------------
extern "C" void kernel_launch(void* const* d_in, const int* in_sizes, int n_in,
                              void* d_out, int out_size, void* d_ws, size_t ws_size,
                              hipStream_t stream)
{
  char* ws = (char*)d_ws;
  bf16_t* H0SEQ  = (bf16_t*)(ws + OFF_H0SEQ);
  bf16_t* OUTSEQ = (bf16_t*)(ws + OFF_OUTSEQ);
  bf16_t* H0BUF  = (bf16_t*)(ws + OFF_H0BUF);
  bf16_t* H1BUF  = (bf16_t*)(ws + OFF_H1BUF);
  float*  XI     = (float*) (ws + OFF_XI);
  float*  RVEC   = (float*) (ws + OFF_RVEC);
  bf16_t* YBF    = (bf16_t*)(ws + OFF_YBF);
  float*  MEMp   = (float*) (ws + OFF_MEM);
  float*  LINKp  = (float*) (ws + OFF_LINK);
  unsigned* BAR  = (unsigned*)(ws + OFF_BAR);
  int*    FLAG   = (int*)   (ws + OFF_BAR + 8);
  bf16_t* XB     = (bf16_t*)(ws + OFF_XB);
  bf16_t* H0B    = (bf16_t*)(ws + OFF_H0B);
  bf16_t* W0     = (bf16_t*)(ws + OFF_W0);
  bf16_t* W1     = (bf16_t*)(ws + OFF_W1);
  bf16_t* W2     = (bf16_t*)(ws + OFF_W2);
  bf16_t* W3     = (bf16_t*)(ws + OFF_W3);
  bf16_t* WIFP   = (bf16_t*)(ws + OFF_WIF);
  bf16_t* WOUTB  = (bf16_t*)(ws + OFF_WOUTB);
  float*  BS0    = (float*) (ws + OFF_BS0);
  float*  BS1    = (float*) (ws + OFF_BS1);
  float*  BIFP   = (float*) (ws + OFF_BIF);
  float*  BOUTF  = (float*) (ws + OFF_BOUTF);

  k_detect<<<1, 256, 0, stream>>>((const unsigned short*)d_in[0], FLAG, BAR);
  k_convert<<<dim3(256, 9), 256, 0, stream>>>(
      d_in[0], d_in[1], d_in[2], d_in[3], d_in[4], d_in[5], d_in[6],
      d_in[7], d_in[8], d_in[9], d_in[10], d_in[11], d_in[12], d_in[13],
      XB, H0B, H0BUF, H1BUF, W0, W1, W2, W3, WIFP, WOUTB,
      BS0, BS1, BIFP, BOUTF, FLAG);
  k_lstm<<<64, 256, 0, stream>>>(XB, H0B, W0, W1, W2, W3, BS0, BS1,
                                 H0BUF, H1BUF, H0SEQ, OUTSEQ, BAR);
  k_xi<<<dim3(128, 8), 256, 0, stream>>>(OUTSEQ, WIFP, BIFP, XI);
  k_mem<<<64, 1024, 0, stream>>>(XI, MEMp, LINKp, RVEC);
  k_tanhy<<<512, 256, 0, stream>>>(OUTSEQ, RVEC, YBF);
  k_out<<<dim3(128, 4), 256, 0, stream>>>(YBF, WOUTB, BOUTF, d_out, FLAG);
}